// Round 3
// baseline (1969.376 us; speedup 1.0000x reference)
//
#include <hip/hip_runtime.h>

#define B_ 64
#define T_ 256
#define E_ 256
#define H_ 256
#define G4 1024   // 4*H
#define L_ 9
#define SENT 0xFFFFFFFFu

typedef __attribute__((ext_vector_type(8))) short bf16x8;
typedef __attribute__((ext_vector_type(4))) float f32x4;
typedef unsigned uint4v __attribute__((ext_vector_type(4)));
typedef _Float16 half2v __attribute__((ext_vector_type(2)));

__device__ __forceinline__ ushort f2bf(float x){
  unsigned u = __float_as_uint(x);
  unsigned r = (u + 0x7FFFu + ((u >> 16) & 1u)) >> 16;
  return (ushort)r;
}
__device__ __forceinline__ ushort f2h(float x){
  _Float16 h = (_Float16)x;
  return __builtin_bit_cast(ushort, h);
}
__device__ __forceinline__ float h2lo(unsigned w){
  return (float)__builtin_bit_cast(half2v, w)[0];
}
__device__ __forceinline__ float h2hi(unsigned w){
  return (float)__builtin_bit_cast(half2v, w)[1];
}
__device__ __forceinline__ float fdot2(unsigned a, unsigned b, float c){
  return __builtin_amdgcn_fdot2(__builtin_bit_cast(half2v, a),
                                __builtin_bit_cast(half2v, b), c, false);
}
__device__ __forceinline__ float fsig(float x){
  return __builtin_amdgcn_rcpf(1.f + __expf(-x));
}
__device__ __forceinline__ float ftanh(float x){
  return 1.f - 2.f * __builtin_amdgcn_rcpf(__expf(2.f * x) + 1.f);
}

// ================= fused prep: cvt_wt | cvt_upk2 | gather | init_hbuf | seqlen ==========
__global__ void k_prep(const int* __restrict__ inp, const float* __restrict__ emb,
                       const float* __restrict__ Wf, const float* __restrict__ Wb,
                       const float* __restrict__ Uf, const float* __restrict__ Ub,
                       ushort* __restrict__ WT, unsigned* __restrict__ Upk2,
                       ushort* __restrict__ X, int* __restrict__ lens,
                       float* __restrict__ out_len, uint4* __restrict__ hbuf4){
  int bid = blockIdx.x, tid = threadIdx.x;
  if (bid < 2048){                                   // W -> bf16 transposed [dir][n][k]
    int idx = bid * 256 + tid;
    int dir = idx >> 18; int rem = idx & 262143;
    int n = rem >> 8, k = rem & 255;
    const float* W = dir ? Wb : Wf;
    WT[idx] = f2bf(W[k * G4 + n]);
  } else if (bid < 3072){                            // U -> f16 [dir][gcol][kpair]
    int idx = (bid - 2048) * 256 + tid;
    int dir = idx >> 17; int rem = idx & 131071;
    int gcol = rem >> 7, p = rem & 127;
    const float* U = dir ? Ub : Uf;
    unsigned lo = f2h(U[(2 * p) * G4 + gcol]);
    unsigned hi = f2h(U[(2 * p + 1) * G4 + gcol]);
    Upk2[idx] = lo | (hi << 16);
  } else if (bid < 5120){                            // X = bf16(emb[inp])
    int idx = (bid - 3072) * 256 + tid;
    int m = idx >> 5, koff = (idx & 31) * 8;
    int tok = inp[m];
    const float* src = emb + (size_t)tok * E_ + koff;
    float4 a = *(const float4*)src;
    float4 b = *(const float4*)(src + 4);
    uint4 o;
    o.x = (unsigned)f2bf(a.x) | ((unsigned)f2bf(a.y) << 16);
    o.y = (unsigned)f2bf(a.z) | ((unsigned)f2bf(a.w) << 16);
    o.z = (unsigned)f2bf(b.x) | ((unsigned)f2bf(b.y) << 16);
    o.w = (unsigned)f2bf(b.z) | ((unsigned)f2bf(b.w) << 16);
    *(uint4*)(X + m * E_ + koff) = o;
  } else if (bid < 9216){                            // hbuf = SENT (16 MB)
    int i = (bid - 5120) * 256 + tid;
    hbuf4[i] = uint4{SENT, SENT, SENT, SENT};
  } else {                                           // seq_lens: 16 blocks x 4 waves
    int w = tid >> 6, lane = tid & 63;
    int b = (bid - 9216) * 4 + w;
    int c = 0;
    for (int t = lane; t < T_; t += 64) c += (inp[b * T_ + t] != 0);
    for (int off = 32; off; off >>= 1) c += __shfl_xor(c, off);
    if (lane == 0){ lens[b] = c; out_len[b] = (float)c; }
  }
}

// ---------------- Z = X @ W + bias  (bf16 MFMA, 128x128 tile) ----------------
__global__ __launch_bounds__(256) void k_gemm(const ushort* __restrict__ X,
        const ushort* __restrict__ WT, const float* __restrict__ bf_,
        const float* __restrict__ bb_, float* __restrict__ Zf, float* __restrict__ Zb){
  int zi = blockIdx.z;
  const ushort* wt = WT + zi * 262144;
  const float* bias = zi ? bb_ : bf_;
  float* Z = zi ? Zb : Zf;
  int m0 = blockIdx.x * 128, n0 = blockIdx.y * 128;
  __shared__ ushort As[128][40];
  __shared__ ushort Bs[128][40];
  int tid = threadIdx.x;
  int sr = tid >> 1, sk = (tid & 1) * 16;
  const ushort* xg = X + (m0 + sr) * E_ + sk;
  const ushort* wg = wt + (n0 + sr) * E_ + sk;
  f32x4 acc[4][4] = {};
  int lane = tid & 63, wv = tid >> 6;
  int wr = wv >> 1, wc = wv & 1;
  int lrow = lane & 15, kf = (lane >> 4) * 8;
  for (int k0 = 0; k0 < E_; k0 += 32){
    uint4 a0 = *(const uint4*)(xg + k0);
    uint4 a1 = *(const uint4*)(xg + k0 + 8);
    uint4 b0 = *(const uint4*)(wg + k0);
    uint4 b1 = *(const uint4*)(wg + k0 + 8);
    *(uint4*)&As[sr][sk]     = a0;  *(uint4*)&As[sr][sk + 8] = a1;
    *(uint4*)&Bs[sr][sk]     = b0;  *(uint4*)&Bs[sr][sk + 8] = b1;
    __syncthreads();
    bf16x8 af[4], bfr[4];
    #pragma unroll
    for (int i = 0; i < 4; i++) af[i]  = *(const bf16x8*)&As[wr * 64 + i * 16 + lrow][kf];
    #pragma unroll
    for (int i = 0; i < 4; i++) bfr[i] = *(const bf16x8*)&Bs[wc * 64 + i * 16 + lrow][kf];
    #pragma unroll
    for (int i = 0; i < 4; i++)
      #pragma unroll
      for (int j = 0; j < 4; j++)
        acc[i][j] = __builtin_amdgcn_mfma_f32_16x16x32_bf16(af[i], bfr[j], acc[i][j], 0, 0, 0);
    __syncthreads();
  }
  int crow = (lane >> 4) * 4;
  #pragma unroll
  for (int j = 0; j < 4; j++){
    int col = n0 + wc * 64 + j * 16 + lrow;
    float bv = bias[col];
    #pragma unroll
    for (int i = 0; i < 4; i++){
      int rbase = m0 + wr * 64 + i * 16 + crow;
      #pragma unroll
      for (int r = 0; r < 4; r++)
        Z[(size_t)(rbase + r) * G4 + col] = acc[i][j][r] + bv;
    }
  }
}

// ================= LSTM recurrence v3: per-lane u64 polling, pipelined =================
// grid 256: bid = s*64 + g, g = dir*32+bg. hg per group: [t][pair p<128] u64,
// u64 = (word b0 | word b1<<32), word = (h[2p] f16 | h[2p+1] f16 <<16).
__global__ __launch_bounds__(512, 2) void k_recur3(
    const float* __restrict__ Zf, const float* __restrict__ Zb,
    const unsigned* __restrict__ Upk2, const int* __restrict__ lens,
    ushort* __restrict__ hf16, ushort* __restrict__ hb16,
    unsigned long long* hbuf){
  int bid = blockIdx.x;
  int g = bid & 63, s = bid >> 6;
  int dir = g >> 5, bg = g & 31;
  int b0 = bg * 2;
  const float* Zx = dir ? Zb : Zf;
  ushort* H = dir ? hb16 : hf16;
  const unsigned* U = Upk2 + dir * 131072;
  unsigned long long* hg = hbuf + (size_t)g * 32768;

  int tid = threadIdx.x;
  int lane = tid & 63, wv = tid >> 6;
  int kh = lane >> 5, cl = lane & 31;
  int c_ = wv * 32 + cl;                     // col in slice, 0..255
  int gate = c_ >> 6, jj = c_ & 63;
  int gc = gate * 256 + s * 64 + jj;         // global gate column

  uint4v uu[16];                             // 128 f16 of U column (this k-half)
  {
    const unsigned* up = U + gc * 128 + kh * 64;
    #pragma unroll
    for (int i = 0; i < 16; i++){
      uu[i] = *(const uint4v*)&up[i * 4];
      asm volatile("" : "+v"(uu[i]));        // pin in VGPRs
    }
  }

  __shared__ float zsh[2][2][256];
  int ab = tid >> 6, aj = tid & 63;          // activation mapping (tid<128)
  int abb = b0 + (ab & 1);
  int alen = (tid < 128) ? lens[abb] : 0;
  float c_st = 0.f, h_st = 0.f;
  int pt = 0;

#define POLL8(W, OFF) { _Pragma("unroll") for (int q = 0; q < 8; q++) \
    W[q] = __hip_atomic_load(hb_ + (OFF) + q, __ATOMIC_RELAXED, __HIP_MEMORY_SCOPE_AGENT); }
#define FIX8(W, OFF) { _Pragma("unroll") for (int q = 0; q < 8; q++){ \
    while (__builtin_expect((unsigned)W[q] == SENT || (unsigned)(W[q] >> 32) == SENT, 0)) \
      W[q] = __hip_atomic_load(hb_ + (OFF) + q, __ATOMIC_RELAXED, __HIP_MEMORY_SCOPE_AGENT); } }
#define DOT8(W, I0) { _Pragma("unroll") for (int e = 0; e < 2; e++){ \
    int i = (I0) + e; \
    a00 = fdot2(uu[i][0], (unsigned)W[e*4+0], a00); a10 = fdot2(uu[i][0], (unsigned)(W[e*4+0]>>32), a10); \
    a01 = fdot2(uu[i][1], (unsigned)W[e*4+1], a01); a11 = fdot2(uu[i][1], (unsigned)(W[e*4+1]>>32), a11); \
    a02 = fdot2(uu[i][2], (unsigned)W[e*4+2], a02); a12 = fdot2(uu[i][2], (unsigned)(W[e*4+2]>>32), a12); \
    a03 = fdot2(uu[i][3], (unsigned)W[e*4+3], a03); a13 = fdot2(uu[i][3], (unsigned)(W[e*4+3]>>32), a13); } }

  for (int s_ = 0; s_ < 256; ++s_){
    int t = dir ? (255 - s_) : s_;
    int buf = s_ & 1;
    float z0p = 0.f, z1p = 0.f, z2p = 0.f, z3p = 0.f;
    if (tid < 128){
      const float* zp = Zx + (size_t)(abb * 256 + t) * G4 + s * 64 + aj;
      z0p = zp[0]; z1p = zp[256]; z2p = zp[512]; z3p = zp[768];
    }
    float a00=0.f,a01=0.f,a02=0.f,a03=0.f,a10=0.f,a11=0.f,a12=0.f,a13=0.f;
    if (s_ > 0){
      const unsigned long long* hb_ = hg + (size_t)pt * 128 + kh * 64;
      unsigned long long A[8], Bv[8];
      POLL8(A, 0);  POLL8(Bv, 8);
      FIX8(A, 0);   DOT8(A, 0);   POLL8(A, 16);
      FIX8(Bv, 8);  DOT8(Bv, 2);  POLL8(Bv, 24);
      FIX8(A, 16);  DOT8(A, 4);   POLL8(A, 32);
      FIX8(Bv, 24); DOT8(Bv, 6);  POLL8(Bv, 40);
      FIX8(A, 32);  DOT8(A, 8);   POLL8(A, 48);
      FIX8(Bv, 40); DOT8(Bv, 10); POLL8(Bv, 56);
      FIX8(A, 48);  DOT8(A, 12);
      FIX8(Bv, 56); DOT8(Bv, 14);
    }
    float zd0 = (a00 + a01) + (a02 + a03);
    float zd1 = (a10 + a11) + (a12 + a13);
    zd0 += __shfl_xor(zd0, 32);
    zd1 += __shfl_xor(zd1, 32);
    if (lane < 32){ zsh[buf][0][c_] = zd0; zsh[buf][1][c_] = zd1; }
    __syncthreads();
    if (tid < 128){
      float zi  = z0p + zsh[buf][ab][aj];
      float zf2 = z1p + zsh[buf][ab][64 + aj];
      float zg  = z2p + zsh[buf][ab][128 + aj];
      float zo  = z3p + zsh[buf][ab][192 + aj];
      if (t < alen){
        c_st = fsig(zf2) * c_st + fsig(zi) * ftanh(zg);
        h_st = fsig(zo) * ftanh(c_st);
      }
      unsigned hw = f2h(h_st);
      unsigned other = (unsigned)__shfl_xor((int)hw, 1);
      if ((aj & 1) == 0){
        unsigned word = hw | (other << 16);
        unsigned* hgw = (unsigned*)(hg + (size_t)t * 128);
        __hip_atomic_store(hgw + ((s * 32 + (aj >> 1)) << 1) + ab, word,
                           __ATOMIC_RELAXED, __HIP_MEMORY_SCOPE_AGENT);
      }
      H[(size_t)(abb * 256 + t) * H_ + s * 64 + aj] = (ushort)hw;
    }
    pt = t;
  }
#undef POLL8
#undef FIX8
#undef DOT8
}

// ---------------- pot = [hf|hb] @ Wd + bd (one wave per row, f16 h) ----------------
__global__ __launch_bounds__(256) void k_pot(const ushort* __restrict__ hf16,
        const ushort* __restrict__ hb16, const float* __restrict__ Wd,
        const float* __restrict__ bd, float* __restrict__ out, int* __restrict__ cnt){
  if (blockIdx.x == 0 && threadIdx.x == 0) *cnt = 0;   // for k_post completion count
  int lane = threadIdx.x & 63, wid = threadIdx.x >> 6;
  int m = blockIdx.x * 4 + wid;
  uint2 ua = *(const uint2*)&hf16[(size_t)m * H_ + lane * 4];
  uint2 ub = *(const uint2*)&hb16[(size_t)m * H_ + lane * 4];
  float av[4] = {h2lo(ua.x), h2hi(ua.x), h2lo(ua.y), h2hi(ua.y)};
  float bv[4] = {h2lo(ub.x), h2hi(ub.x), h2lo(ub.y), h2hi(ub.y)};
  float acc[9];
  #pragma unroll
  for (int l = 0; l < 9; l++) acc[l] = 0.f;
  #pragma unroll
  for (int i = 0; i < 4; i++){
    int r = lane * 4 + i;
    #pragma unroll
    for (int l = 0; l < 9; l++)
      acc[l] += av[i] * Wd[r * 9 + l] + bv[i] * Wd[(H_ + r) * 9 + l];
  }
  #pragma unroll
  for (int off = 32; off; off >>= 1)
    #pragma unroll
    for (int l = 0; l < 9; l++) acc[l] += __shfl_xor(acc[l], off);
  if (lane == 0){
    #pragma unroll
    for (int l = 0; l < 9; l++) out[(size_t)m * 9 + l] = acc[l] + bd[l];
  }
}

// ---------------- CRF log-likelihood + loss (fused, last-block reduce) ----------------
__global__ void k_post(const float* __restrict__ out, const int* __restrict__ tags,
                       const float* __restrict__ trans, const int* __restrict__ lens,
                       float* __restrict__ lln, int* cnt, float* __restrict__ loss_out){
  int b = blockIdx.x, lane = threadIdx.x;
  int len = lens[b];
  const float* pot = out + (size_t)b * T_ * 9;
  float up = 0.f, bp = 0.f;
  for (int t = lane; t < T_; t += 64){
    int tg = tags[b * T_ + t];
    if (t < len) up += pot[t * 9 + tg];
    if (t + 1 < len){
      int tg2 = tags[b * T_ + t + 1];
      bp += trans[tg * 9 + tg2];
    }
  }
  for (int off = 32; off; off >>= 1){ up += __shfl_xor(up, off); bp += __shfl_xor(bp, off); }
  float alpha = 0.f;
  if (lane < 9){
    float tr[9];
    #pragma unroll
    for (int i = 0; i < 9; i++) tr[i] = trans[i * 9 + lane];
    alpha = pot[lane];
    for (int t = 1; t < T_; ++t){
      float v[9];
      #pragma unroll
      for (int i = 0; i < 9; i++) v[i] = __shfl(alpha, i) + tr[i];
      float mx = v[0];
      #pragma unroll
      for (int i = 1; i < 9; i++) mx = fmaxf(mx, v[i]);
      float sum = 0.f;
      #pragma unroll
      for (int i = 0; i < 9; i++) sum += __expf(v[i] - mx);
      float an = pot[t * 9 + lane] + mx + __logf(sum);
      if (t < len) alpha = an;
    }
  }
  float mx2 = -3.4e38f;
  for (int i = 0; i < 9; i++){ float a = __shfl(alpha, i); mx2 = fmaxf(mx2, a); }
  float s2 = 0.f;
  for (int i = 0; i < 9; i++){ float a = __shfl(alpha, i); s2 += __expf(a - mx2); }
  float lse = mx2 + __logf(s2);
  __shared__ int lastf;
  if (lane == 0){
    __hip_atomic_store(&lln[b], (up + bp - lse) / (float)len,
                       __ATOMIC_RELAXED, __HIP_MEMORY_SCOPE_AGENT);
    int old = __hip_atomic_fetch_add(cnt, 1, __ATOMIC_ACQ_REL, __HIP_MEMORY_SCOPE_AGENT);
    lastf = (old == 63);
  }
  __syncthreads();
  if (lastf){
    float v = __hip_atomic_load(&lln[lane], __ATOMIC_RELAXED, __HIP_MEMORY_SCOPE_AGENT);
    for (int off = 32; off; off >>= 1) v += __shfl_xor(v, off);
    if (lane == 0) loss_out[0] = -v * (1.f / 64.f);
  }
}

extern "C" void kernel_launch(void* const* d_in, const int* in_sizes, int n_in,
                              void* d_out, int out_size, void* d_ws, size_t ws_size,
                              hipStream_t stream) {
  (void)in_sizes; (void)n_in; (void)out_size; (void)ws_size;
  const int*   inp   = (const int*)  d_in[0];
  const int*   tags  = (const int*)  d_in[1];
  const float* emb   = (const float*)d_in[2];
  const float* Wf    = (const float*)d_in[3];
  const float* Uf    = (const float*)d_in[4];
  const float* bfv   = (const float*)d_in[5];
  const float* Wb    = (const float*)d_in[6];
  const float* Ub    = (const float*)d_in[7];
  const float* bbv   = (const float*)d_in[8];
  const float* Wd    = (const float*)d_in[9];
  const float* bd    = (const float*)d_in[10];
  const float* trans = (const float*)d_in[11];
  float* out = (float*)d_out;

  char* ws = (char*)d_ws;
  // layout (bytes), end = 178258436 <= R0-proven extent
  unsigned* Upk2 = (unsigned*)(ws);                         // 1 MB
  ushort*   WT16 = (ushort*)  (ws + 1048576);               // 1 MB
  ushort*   Xbf  = (ushort*)  (ws + 2097152);               // 8 MB
  unsigned long long* hbuf = (unsigned long long*)(ws + 10485760); // 16 MB
  int*      cnt  = (int*)     (ws + 10485760);              // aliases hbuf[0] (dead by k_pot)
  float*    Zf   = (float*)   (ws + 27262976);              // 64 MB
  float*    Zb   = (float*)   (ws + 94371840);              // 64 MB
  ushort*   hf16 = (ushort*)  (ws + 161480704);             // 8 MB
  ushort*   hb16 = (ushort*)  (ws + 169869312);             // 8 MB
  int*      lens = (int*)     (ws + 178257920);             // 256 B
  float*    lln  = (float*)   (ws + 178258176);             // 256 B

  k_prep<<<9232, 256, 0, stream>>>(inp, emb, Wf, Wb, Uf, Ub, WT16, Upk2, Xbf,
                                   lens, out + 147456, (uint4*)hbuf);
  k_gemm<<<dim3(128, 8, 2), 256, 0, stream>>>(Xbf, WT16, bfv, bbv, Zf, Zb);
  k_recur3<<<256, 512, 0, stream>>>(Zf, Zb, Upk2, lens, hf16, hb16, hbuf);
  k_pot<<<4096, 256, 0, stream>>>(hf16, hb16, Wd, bd, out, cnt);
  k_post<<<64, 64, 0, stream>>>(out, tags, trans, lens, lln, cnt, out + 147520);
}